// Round 2
// baseline (1459.196 us; speedup 1.0000x reference)
//
#include <hip/hip_runtime.h>
#include <stdint.h>

// BinaryConv: out = sign(conv2d(sign(x), sign(w), pad=1) + bias)
// x: [32,256,56,56] f32, w: [256,256,3,3] f32, bias: [256] f32, out: [32,256,56,56] f32
// XNOR-popcount formulation, exact integer arithmetic (output can be exactly 0).

#define NB   32
#define CC   256
#define HH   56
#define WW   56
#define OO   256
#define PHH  58
#define PWW  58
#define SPAD (PHH*PWW)   // 3364 padded spatial
#define SS   (HH*WW)     // 3136 spatial
#define CWN  4           // 256 channels / 64 bits

// ---------------- pack x: [n][c][h][w] f32 -> [n][cw][ph][pw] u64 (padded, pad=0) ----
__global__ __launch_bounds__(256) void pack_x_kernel(const float* __restrict__ x,
                                                     uint64_t* __restrict__ px) {
    int tid = threadIdx.x;
    int sp  = blockIdx.x * 256 + tid;
    int cw  = blockIdx.y;
    int n   = blockIdx.z;
    if (sp >= SPAD) return;
    int ph = sp / PWW, pw_ = sp % PWW;
    uint64_t* dst = px + (((size_t)n * CWN + cw) * SPAD + sp);
    if (ph == 0 || ph == PHH - 1 || pw_ == 0 || pw_ == PWW - 1) { *dst = 0ull; return; }
    int h = ph - 1, w = pw_ - 1;
    const float* src = x + ((size_t)(n * CC + cw * 64)) * SS + (h * WW + w);
    uint32_t lo = 0u, hi = 0u;
#pragma unroll
    for (int j = 0; j < 32; ++j) {
        float v = src[(size_t)j * SS];
        lo |= (v > 0.0f ? 1u : 0u) << j;
    }
#pragma unroll
    for (int j = 0; j < 32; ++j) {
        float v = src[(size_t)(j + 32) * SS];
        hi |= (v > 0.0f ? 1u : 0u) << j;
    }
    *dst = ((uint64_t)hi << 32) | (uint64_t)lo;
}

// ---------------- pack w: [o][c][kh][kw] f32 -> [o][t][cw] u64, t = kh*3+kw ----------
__global__ __launch_bounds__(256) void pack_w_kernel(const float* __restrict__ wgt,
                                                     uint64_t* __restrict__ pwb) {
    int lane = threadIdx.x & 63;
    int wave = threadIdx.x >> 6;
    int wi   = blockIdx.x * 4 + wave;           // word index: o*36 + t*4 + cw
    if (wi >= OO * 9 * CWN) return;
    int o = wi / 36, rem = wi % 36, t = rem >> 2, cw = rem & 3;
    int c = cw * 64 + lane;
    float v = wgt[(size_t)(o * CC + c) * 9 + t];
    uint64_t m = __ballot(v > 0.0f);            // bit lane <-> channel cw*64+lane
    if (lane == 0) pwb[wi] = m;
}

// ---------------- K table: per (border-class, o) base constant -----------------------
// sum_true = K[cls][o] - 2*P   where P = popc over all 36 words with pad x-words = 0.
__global__ __launch_bounds__(256) void build_k_kernel(const uint64_t* __restrict__ pwb,
                                                      int* __restrict__ ktab) {
    int o = threadIdx.x;   // one block of 256
    int pops[9];
#pragma unroll
    for (int t = 0; t < 9; ++t) {
        int p = 0;
#pragma unroll
        for (int cw = 0; cw < 4; ++cw) p += __popcll(pwb[o * 36 + t * 4 + cw]);
        pops[t] = p;
    }
#pragma unroll
    for (int cls = 0; cls < 9; ++cls) {
        int vf = cls / 3, hf = cls % 3;   // 0 none, 1 top/left, 2 bot/right
        int K = 9 * CC;
#pragma unroll
        for (int t = 0; t < 9; ++t) {
            int r = t / 3, k = t % 3;
            bool inv = (vf == 1 && r == 0) || (vf == 2 && r == 2) ||
                       (hf == 1 && k == 0) || (hf == 2 && k == 2);
            if (inv) K -= (CC - 2 * pops[t]);
        }
        ktab[cls * OO + o] = K;
    }
}

// ---------------- binary conv: popcount inner loop -----------------------------------
// One thread = one (n, pixel); 64 output channels per thread (blockIdx.y selects group).
// Patch (36 u64 = 72 u32) is held in VGPRs for the whole oi loop: launch_bounds(256,4)
// allows 128 VGPRs. Explicit u32 popcount-accumulate folds to xor + v_bcnt (accum).
__global__ __launch_bounds__(256, 4) void bconv_kernel(const uint64_t* __restrict__ px,
                                                       const uint64_t* __restrict__ pwb,
                                                       const int* __restrict__ ktab,
                                                       const float* __restrict__ bias,
                                                       float* __restrict__ out) {
    int g = blockIdx.x * 256 + threadIdx.x;   // 0 .. 100351 (= 32*3136, exact)
    int n = g / SS;
    int sid = g - n * SS;
    int obase = blockIdx.y * 64;
    int h = sid / WW, w = sid - h * WW;
    int vf = (h == 0) ? 1 : ((h == HH - 1) ? 2 : 0);
    int hf = (w == 0) ? 1 : ((w == WW - 1) ? 2 : 0);
    const int* krow = ktab + (vf * 3 + hf) * OO;

    // patch in registers, laid out to match pwb word order: idx = (t*4+cw)*2 + half
    uint32_t pat[72];
#pragma unroll
    for (int cw = 0; cw < 4; ++cw) {
        const uint64_t* base = px + ((size_t)(n * CWN + cw)) * SPAD + h * PWW + w;
#pragma unroll
        for (int r = 0; r < 3; ++r) {
#pragma unroll
            for (int k = 0; k < 3; ++k) {
                uint64_t v = base[r * PWW + k];
                int idx = ((r * 3 + k) * 4 + cw) * 2;
                pat[idx]     = (uint32_t)v;
                pat[idx + 1] = (uint32_t)(v >> 32);
            }
        }
    }

    float* orow = out + ((size_t)(n * OO + obase)) * SS + sid;
    const uint32_t* wb = (const uint32_t*)(pwb + (size_t)obase * 36);
#pragma unroll 2
    for (int oi = 0; oi < 64; ++oi) {
        const uint32_t* wv = wb + oi * 72;    // wave-uniform -> s_load
        int p0 = 0, p1 = 0, p2 = 0, p3 = 0;
#pragma unroll
        for (int t = 0; t < 9; ++t) {
            int b = t * 8;
            p0 = __popc(pat[b + 0] ^ wv[b + 0]) + p0;
            p0 = __popc(pat[b + 1] ^ wv[b + 1]) + p0;
            p1 = __popc(pat[b + 2] ^ wv[b + 2]) + p1;
            p1 = __popc(pat[b + 3] ^ wv[b + 3]) + p1;
            p2 = __popc(pat[b + 4] ^ wv[b + 4]) + p2;
            p2 = __popc(pat[b + 5] ^ wv[b + 5]) + p2;
            p3 = __popc(pat[b + 6] ^ wv[b + 6]) + p3;
            p3 = __popc(pat[b + 7] ^ wv[b + 7]) + p3;
        }
        int P = (p0 + p1) + (p2 + p3);
        float v = (float)(krow[obase + oi] - 2 * P) + bias[obase + oi];
        float res = (v > 0.0f) ? 1.0f : ((v < 0.0f) ? -1.0f : 0.0f);
        orow[(size_t)oi * SS] = res;
    }
}

extern "C" void kernel_launch(void* const* d_in, const int* in_sizes, int n_in,
                              void* d_out, int out_size, void* d_ws, size_t ws_size,
                              hipStream_t stream) {
    const float* x    = (const float*)d_in[0];
    const float* wgt  = (const float*)d_in[1];
    const float* bias = (const float*)d_in[2];
    float* out = (float*)d_out;

    // workspace layout
    size_t px_bytes = (size_t)NB * CWN * SPAD * 8;          // 3,444,736
    size_t pw_off   = px_bytes;                             // 8B aligned
    size_t pw_bytes = (size_t)OO * 9 * CWN * 8;             // 73,728
    size_t k_off    = pw_off + pw_bytes;
    uint64_t* px  = (uint64_t*)d_ws;
    uint64_t* pwb = (uint64_t*)((char*)d_ws + pw_off);
    int*      kt  = (int*)((char*)d_ws + k_off);

    dim3 gpx((SPAD + 255) / 256, CWN, NB);                  // 14 x 4 x 32
    pack_x_kernel<<<gpx, 256, 0, stream>>>(x, px);

    int nwords = OO * 9 * CWN;                              // 9216
    pack_w_kernel<<<dim3((nwords + 3) / 4), 256, 0, stream>>>(wgt, pwb);

    build_k_kernel<<<dim3(1), 256, 0, stream>>>(pwb, kt);

    dim3 gcv(NB * SS / 256, OO / 64, 1);                    // 392 x 4, exact
    bconv_kernel<<<gcv, 256, 0, stream>>>(px, pwb, kt, bias, out);
}

// Round 3
// 303.549 us; speedup vs baseline: 4.8071x; 4.8071x over previous
//
#include <hip/hip_runtime.h>
#include <stdint.h>

// BinaryConv: out = sign(conv2d(sign(x), sign(w), pad=1) + bias)
// x: [32,256,56,56] f32, w: [256,256,3,3] f32, bias: [256] f32, out: [32,256,56,56] f32
// XNOR-popcount formulation, exact integer arithmetic (output can be exactly 0).

#define NB   32
#define CC   256
#define HH   56
#define WW   56
#define OO   256
#define PHH  58
#define PWW  58
#define SPAD (PHH*PWW)   // 3364 padded spatial
#define SS   (HH*WW)     // 3136 spatial
#define CWN  4           // 256 channels / 64 bits

// ---------------- pack x: [n][c][h][w] f32 -> [n][cw][ph][pw] u64 (padded, pad=0) ----
__global__ __launch_bounds__(256) void pack_x_kernel(const float* __restrict__ x,
                                                     uint64_t* __restrict__ px) {
    int tid = threadIdx.x;
    int sp  = blockIdx.x * 256 + tid;
    int cw  = blockIdx.y;
    int n   = blockIdx.z;
    if (sp >= SPAD) return;
    int ph = sp / PWW, pw_ = sp % PWW;
    uint64_t* dst = px + (((size_t)n * CWN + cw) * SPAD + sp);
    if (ph == 0 || ph == PHH - 1 || pw_ == 0 || pw_ == PWW - 1) { *dst = 0ull; return; }
    int h = ph - 1, w = pw_ - 1;
    const float* src = x + ((size_t)(n * CC + cw * 64)) * SS + (h * WW + w);
    uint32_t lo = 0u, hi = 0u;
#pragma unroll
    for (int j = 0; j < 32; ++j) {
        float v = src[(size_t)j * SS];
        lo |= (v > 0.0f ? 1u : 0u) << j;
    }
#pragma unroll
    for (int j = 0; j < 32; ++j) {
        float v = src[(size_t)(j + 32) * SS];
        hi |= (v > 0.0f ? 1u : 0u) << j;
    }
    *dst = ((uint64_t)hi << 32) | (uint64_t)lo;
}

// ---------------- pack w: [o][c][kh][kw] f32 -> [o][t][cw] u64, t = kh*3+kw ----------
__global__ __launch_bounds__(256) void pack_w_kernel(const float* __restrict__ wgt,
                                                     uint64_t* __restrict__ pwb) {
    int lane = threadIdx.x & 63;
    int wave = threadIdx.x >> 6;
    int wi   = blockIdx.x * 4 + wave;           // word index: o*36 + t*4 + cw
    if (wi >= OO * 9 * CWN) return;
    int o = wi / 36, rem = wi % 36, t = rem >> 2, cw = rem & 3;
    int c = cw * 64 + lane;
    float v = wgt[(size_t)(o * CC + c) * 9 + t];
    uint64_t m = __ballot(v > 0.0f);            // bit lane <-> channel cw*64+lane
    if (lane == 0) pwb[wi] = m;
}

// ---------------- K table: per (border-class, o) base constant -----------------------
// sum_true = K[cls][o] - 2*P   where P = popc over all 36 words with pad x-words = 0.
__global__ __launch_bounds__(256) void build_k_kernel(const uint64_t* __restrict__ pwb,
                                                      int* __restrict__ ktab) {
    int o = threadIdx.x;   // one block of 256
    int pops[9];
#pragma unroll
    for (int t = 0; t < 9; ++t) {
        int p = 0;
#pragma unroll
        for (int cw = 0; cw < 4; ++cw) p += __popcll(pwb[o * 36 + t * 4 + cw]);
        pops[t] = p;
    }
#pragma unroll
    for (int cls = 0; cls < 9; ++cls) {
        int vf = cls / 3, hf = cls % 3;   // 0 none, 1 top/left, 2 bot/right
        int K = 9 * CC;
#pragma unroll
        for (int t = 0; t < 9; ++t) {
            int r = t / 3, k = t % 3;
            bool inv = (vf == 1 && r == 0) || (vf == 2 && r == 2) ||
                       (hf == 1 && k == 0) || (hf == 2 && k == 2);
            if (inv) K -= (CC - 2 * pops[t]);
        }
        ktab[cls * OO + o] = K;
    }
}

// ---------------- binary conv: popcount inner loop -----------------------------------
// One thread = one (n, pixel); 64 output channels per block-y. Patch (72 u32) lives in
// VGPRs (launch_bounds(256,3) -> ~170 cap, no spill). Weights for the 64 channels are
// staged once in LDS (18.4 KB) and read as uniform-address uint4 broadcasts, so the
// weight path costs 0 VGPR pressure and no per-oi global traffic.
__global__ __launch_bounds__(256, 3) void bconv_kernel(const uint64_t* __restrict__ px,
                                                       const uint64_t* __restrict__ pwb,
                                                       const int* __restrict__ ktab,
                                                       const float* __restrict__ bias,
                                                       float* __restrict__ out) {
    __shared__ uint4 ws[64 * 18];                 // 64 oi x 72 u32 = 18432 B
    int tid = threadIdx.x;
    int obase = blockIdx.y * 64;

    // stage weights (coalesced uint4): 1152 uint4 over 256 threads
    const uint4* wsrc = (const uint4*)(pwb + (size_t)obase * 36);
    for (int i = tid; i < 64 * 18; i += 256) ws[i] = wsrc[i];
    __syncthreads();

    int g = blockIdx.x * 256 + tid;               // 0 .. 100351 (= 32*3136, exact)
    int n = g / SS;
    int sid = g - n * SS;
    int h = sid / WW, w = sid - h * WW;
    int vf = (h == 0) ? 1 : ((h == HH - 1) ? 2 : 0);
    int hf = (w == 0) ? 1 : ((w == WW - 1) ? 2 : 0);
    const int* krow = ktab + (vf * 3 + hf) * OO;

    // patch in registers, word order matches pwb: idx = (t*4+cw)*2 + half
    uint32_t pat[72];
#pragma unroll
    for (int cw = 0; cw < 4; ++cw) {
        const uint64_t* base = px + ((size_t)(n * CWN + cw)) * SPAD + h * PWW + w;
#pragma unroll
        for (int r = 0; r < 3; ++r) {
#pragma unroll
            for (int k = 0; k < 3; ++k) {
                uint64_t v = base[r * PWW + k];
                int idx = ((r * 3 + k) * 4 + cw) * 2;
                pat[idx]     = (uint32_t)v;
                pat[idx + 1] = (uint32_t)(v >> 32);
            }
        }
    }

    float* orow = out + ((size_t)(n * OO + obase)) * SS + sid;
#pragma unroll 1
    for (int oi = 0; oi < 64; ++oi) {
        const uint4* wv = &ws[oi * 18];           // uniform address -> LDS broadcast
        int p0 = 0, p1 = 0, p2 = 0, p3 = 0;
#pragma unroll
        for (int t = 0; t < 9; ++t) {
            uint4 wa = wv[t * 2 + 0];
            uint4 wb = wv[t * 2 + 1];
            int b = t * 8;
            p0 = __popc(pat[b + 0] ^ wa.x) + p0;
            p0 = __popc(pat[b + 1] ^ wa.y) + p0;
            p1 = __popc(pat[b + 2] ^ wa.z) + p1;
            p1 = __popc(pat[b + 3] ^ wa.w) + p1;
            p2 = __popc(pat[b + 4] ^ wb.x) + p2;
            p2 = __popc(pat[b + 5] ^ wb.y) + p2;
            p3 = __popc(pat[b + 6] ^ wb.z) + p3;
            p3 = __popc(pat[b + 7] ^ wb.w) + p3;
        }
        int P = (p0 + p1) + (p2 + p3);
        float v = (float)(krow[obase + oi] - 2 * P) + bias[obase + oi];
        float res = (v > 0.0f) ? 1.0f : ((v < 0.0f) ? -1.0f : 0.0f);
        orow[(size_t)oi * SS] = res;
    }
}

extern "C" void kernel_launch(void* const* d_in, const int* in_sizes, int n_in,
                              void* d_out, int out_size, void* d_ws, size_t ws_size,
                              hipStream_t stream) {
    const float* x    = (const float*)d_in[0];
    const float* wgt  = (const float*)d_in[1];
    const float* bias = (const float*)d_in[2];
    float* out = (float*)d_out;

    // workspace layout
    size_t px_bytes = (size_t)NB * CWN * SPAD * 8;          // 3,444,736
    size_t pw_off   = px_bytes;                             // 8B aligned
    size_t pw_bytes = (size_t)OO * 9 * CWN * 8;             // 73,728
    size_t k_off    = pw_off + pw_bytes;
    uint64_t* px  = (uint64_t*)d_ws;
    uint64_t* pwb = (uint64_t*)((char*)d_ws + pw_off);
    int*      kt  = (int*)((char*)d_ws + k_off);

    dim3 gpx((SPAD + 255) / 256, CWN, NB);                  // 14 x 4 x 32
    pack_x_kernel<<<gpx, 256, 0, stream>>>(x, px);

    int nwords = OO * 9 * CWN;                              // 9216
    pack_w_kernel<<<dim3((nwords + 3) / 4), 256, 0, stream>>>(wgt, pwb);

    build_k_kernel<<<dim3(1), 256, 0, stream>>>(pwb, kt);

    dim3 gcv(NB * SS / 256, OO / 64, 1);                    // 392 x 4, exact
    bconv_kernel<<<gcv, 256, 0, stream>>>(px, pwb, kt, bias, out);
}

// Round 4
// 163.023 us; speedup vs baseline: 8.9509x; 1.8620x over previous
//
#include <hip/hip_runtime.h>
#include <stdint.h>

// BinaryConv: out = sign(conv2d(sign(x), sign(w), pad=1) + bias)
// x: [32,256,56,56] f32, w: [256,256,3,3] f32, bias: [256] f32, out: [32,256,56,56] f32
// XNOR-popcount formulation, exact integer arithmetic (output can be exactly 0).

#define NB   32
#define CC   256
#define HH   56
#define WW   56
#define OO   256
#define PHH  58
#define PWW  58
#define SPAD (PHH*PWW)   // 3364 padded spatial
#define SS   (HH*WW)     // 3136 spatial
#define CWN  4           // 256 channels / 64 bits

// ---------------- pack x: [n][c][h][w] f32 -> [n][cw][ph][pw] u64 (padded, pad=0) ----
__global__ __launch_bounds__(256) void pack_x_kernel(const float* __restrict__ x,
                                                     uint64_t* __restrict__ px) {
    int tid = threadIdx.x;
    int sp  = blockIdx.x * 256 + tid;
    int cw  = blockIdx.y;
    int n   = blockIdx.z;
    if (sp >= SPAD) return;
    int ph = sp / PWW, pw_ = sp % PWW;
    uint64_t* dst = px + (((size_t)n * CWN + cw) * SPAD + sp);
    if (ph == 0 || ph == PHH - 1 || pw_ == 0 || pw_ == PWW - 1) { *dst = 0ull; return; }
    int h = ph - 1, w = pw_ - 1;
    const float* src = x + ((size_t)(n * CC + cw * 64)) * SS + (h * WW + w);
    uint32_t lo = 0u, hi = 0u;
#pragma unroll
    for (int j = 0; j < 32; ++j) {
        float v = src[(size_t)j * SS];
        lo |= (v > 0.0f ? 1u : 0u) << j;
    }
#pragma unroll
    for (int j = 0; j < 32; ++j) {
        float v = src[(size_t)(j + 32) * SS];
        hi |= (v > 0.0f ? 1u : 0u) << j;
    }
    *dst = ((uint64_t)hi << 32) | (uint64_t)lo;
}

// ---------------- pack w: [o][c][kh][kw] f32 -> [o][t][cw] u64, t = kh*3+kw ----------
__global__ __launch_bounds__(256) void pack_w_kernel(const float* __restrict__ wgt,
                                                     uint64_t* __restrict__ pwb) {
    int lane = threadIdx.x & 63;
    int wave = threadIdx.x >> 6;
    int wi   = blockIdx.x * 4 + wave;           // word index: o*36 + t*4 + cw
    if (wi >= OO * 9 * CWN) return;
    int o = wi / 36, rem = wi % 36, t = rem >> 2, cw = rem & 3;
    int c = cw * 64 + lane;
    float v = wgt[(size_t)(o * CC + c) * 9 + t];
    uint64_t m = __ballot(v > 0.0f);            // bit lane <-> channel cw*64+lane
    if (lane == 0) pwb[wi] = m;
}

// ---------------- K table: per (border-class, o) base constant -----------------------
// sum_true = K[cls][o] - 2*P   where P = popc over all 36 words with pad x-words = 0.
__global__ __launch_bounds__(256) void build_k_kernel(const uint64_t* __restrict__ pwb,
                                                      int* __restrict__ ktab) {
    int o = threadIdx.x;   // one block of 256
    int pops[9];
#pragma unroll
    for (int t = 0; t < 9; ++t) {
        int p = 0;
#pragma unroll
        for (int cw = 0; cw < 4; ++cw) p += __popcll(pwb[o * 36 + t * 4 + cw]);
        pops[t] = p;
    }
#pragma unroll
    for (int cls = 0; cls < 9; ++cls) {
        int vf = cls / 3, hf = cls % 3;   // 0 none, 1 top/left, 2 bot/right
        int K = 9 * CC;
#pragma unroll
        for (int t = 0; t < 9; ++t) {
            int r = t / 3, k = t % 3;
            bool inv = (vf == 1 && r == 0) || (vf == 2 && r == 2) ||
                       (hf == 1 && k == 0) || (hf == 2 && k == 2);
            if (inv) K -= (CC - 2 * pops[t]);
        }
        ktab[cls * OO + o] = K;
    }
}

// ---------------- binary conv: popcount inner loop -----------------------------------
// One thread = one (n, pixel) x 32 output channels (blockIdx.y picks the group of 32).
// Residency inverted vs earlier rounds: acc[32] stays in VGPRs; the patch is STREAMED
// one tap (8 u32, L2-hit) at a time, so per-thread register demand is ~60 VGPRs and
// cannot spill. Weights are wave-uniform -> compiler scalarizes to s_load (SMEM pipe),
// costing zero VGPRs and no LDS/barrier. VMEM:VALU interleave per tap = 4:512.
__global__ __launch_bounds__(256, 4) void bconv_kernel(const uint64_t* __restrict__ px,
                                                       const uint64_t* __restrict__ pwb,
                                                       const int* __restrict__ ktab,
                                                       const float* __restrict__ bias,
                                                       float* __restrict__ out) {
    int g = blockIdx.x * 256 + threadIdx.x;   // 0 .. 100351 (= 32*3136, exact)
    int n = g / SS;
    int sid = g - n * SS;
    int obase = blockIdx.y * 32;
    int h = sid / WW, w = sid - h * WW;
    int vf = (h == 0) ? 1 : ((h == HH - 1) ? 2 : 0);
    int hf = (w == 0) ? 1 : ((w == WW - 1) ? 2 : 0);
    const int* krow = ktab + (vf * 3 + hf) * OO + obase;

    const uint64_t* pb = px + (size_t)n * CWN * SPAD + h * PWW + w;  // +cw*SPAD per plane
    const uint32_t* wb = (const uint32_t*)pwb + (size_t)obase * 72;  // [oi][t*8 + 2*cw + half]

    uint32_t acc[32];
#pragma unroll
    for (int i = 0; i < 32; ++i) acc[i] = 0u;

#pragma unroll 1
    for (int r = 0; r < 3; ++r) {
#pragma unroll 1
        for (int k = 0; k < 3; ++k) {
            int off = r * PWW + k;
            uint64_t q0 = pb[off];
            uint64_t q1 = pb[SPAD + off];
            uint64_t q2 = pb[2 * SPAD + off];
            uint64_t q3 = pb[3 * SPAD + off];
            uint32_t pa0 = (uint32_t)q0, pa1 = (uint32_t)(q0 >> 32);
            uint32_t pa2 = (uint32_t)q1, pa3 = (uint32_t)(q1 >> 32);
            uint32_t pa4 = (uint32_t)q2, pa5 = (uint32_t)(q2 >> 32);
            uint32_t pa6 = (uint32_t)q3, pa7 = (uint32_t)(q3 >> 32);
            int t8 = (r * 3 + k) * 8;
#pragma unroll
            for (int oi = 0; oi < 32; ++oi) {
                const uint32_t* wv = wb + oi * 72 + t8;  // wave-uniform -> s_load
                uint32_t a = acc[oi];
                a = __popc(pa0 ^ wv[0]) + a;
                a = __popc(pa1 ^ wv[1]) + a;
                a = __popc(pa2 ^ wv[2]) + a;
                a = __popc(pa3 ^ wv[3]) + a;
                a = __popc(pa4 ^ wv[4]) + a;
                a = __popc(pa5 ^ wv[5]) + a;
                a = __popc(pa6 ^ wv[6]) + a;
                a = __popc(pa7 ^ wv[7]) + a;
                acc[oi] = a;
            }
        }
    }

    float* orow = out + ((size_t)(n * OO + obase)) * SS + sid;
#pragma unroll
    for (int oi = 0; oi < 32; ++oi) {
        int s = krow[oi] - 2 * (int)acc[oi];
        float v = (float)s + bias[obase + oi];
        float res = (v > 0.0f) ? 1.0f : ((v < 0.0f) ? -1.0f : 0.0f);
        orow[(size_t)oi * SS] = res;
    }
}

extern "C" void kernel_launch(void* const* d_in, const int* in_sizes, int n_in,
                              void* d_out, int out_size, void* d_ws, size_t ws_size,
                              hipStream_t stream) {
    const float* x    = (const float*)d_in[0];
    const float* wgt  = (const float*)d_in[1];
    const float* bias = (const float*)d_in[2];
    float* out = (float*)d_out;

    // workspace layout
    size_t px_bytes = (size_t)NB * CWN * SPAD * 8;          // 3,444,736
    size_t pw_off   = px_bytes;                             // 8B aligned
    size_t pw_bytes = (size_t)OO * 9 * CWN * 8;             // 73,728
    size_t k_off    = pw_off + pw_bytes;
    uint64_t* px  = (uint64_t*)d_ws;
    uint64_t* pwb = (uint64_t*)((char*)d_ws + pw_off);
    int*      kt  = (int*)((char*)d_ws + k_off);

    dim3 gpx((SPAD + 255) / 256, CWN, NB);                  // 14 x 4 x 32
    pack_x_kernel<<<gpx, 256, 0, stream>>>(x, px);

    int nwords = OO * 9 * CWN;                              // 9216
    pack_w_kernel<<<dim3((nwords + 3) / 4), 256, 0, stream>>>(wgt, pwb);

    build_k_kernel<<<dim3(1), 256, 0, stream>>>(pwb, kt);

    dim3 gcv(NB * SS / 256, OO / 32, 1);                    // 392 x 8, exact
    bconv_kernel<<<gcv, 256, 0, stream>>>(px, pwb, kt, bias, out);
}